// Round 7
// baseline (179.070 us; speedup 1.0000x reference)
//
#include <hip/hip_runtime.h>
#include <math.h>

#define S_LEN 512
#define BATCH 16
#define DIN   512
#define DF    512
#define NMIX  10
#define NCHAR 1024
#define DCTX  256
#define M_ROWS (S_LEN*BATCH)   // 8192

// d_out layout (tuple flattened in return order)
#define OFF_CTXOUT 0
#define OFF_ATTN   (S_LEN*BATCH*DCTX)
#define OFF_MEANS  (OFF_ATTN + S_LEN*BATCH*NCHAR)
#define OFF_VARS   (OFF_MEANS + S_LEN*BATCH*NMIX)
#define OFF_WTS    (OFF_VARS  + S_LEN*BATCH*NMIX)

// scratch layout in d_ws (byte offsets)
#define WS_XH    0            // f16  8 MB   (8192x512)
#define WS_W1H   (8u<<20)     // f16  512 KB
#define WS_W2T   (9u<<20)     // f32  64 KB  (32x512 padded)
#define WS_HH    (10u<<20)    // f16  8 MB
#define WS_CTXH  (18u<<20)    // f16  8 MB
#define WS_ATTNH (26u<<20)    // f16  16.8 MB
#define WS_DELTA (44u<<20)    // f32  327 KB (8192x10)

#define NX4     1048576
#define NW14    65536
#define NCTX4   1048576
#define CVT4    (NX4 + NW14 + NCTX4)
#define CVT_BLOCKS (CVT4/256)
#define W2T_BLOCKS 64

typedef float    f32x16 __attribute__((ext_vector_type(16)));
typedef _Float16 f16x8  __attribute__((ext_vector_type(8)));

__device__ __forceinline__ unsigned short f2h(float x) {
    union { _Float16 h; unsigned short u; } cv;
    cv.h = (_Float16)x;
    return cv.u;
}
__device__ __forceinline__ ushort4 cvt4(float4 v) {
    ushort4 o; o.x = f2h(v.x); o.y = f2h(v.y); o.z = f2h(v.z); o.w = f2h(v.w);
    return o;
}

// ---------------------------------------------------------------------------
// Kernel 0: convert X,W1,ctx -> f16 scratch; build W2^T (fp32, 32 rows).
// ---------------------------------------------------------------------------
__global__ __launch_bounds__(256) void convert_kernel(
    const float* __restrict__ X, const float* __restrict__ W1,
    const float* __restrict__ ctx, const float* __restrict__ W2,
    unsigned short* __restrict__ Xh, unsigned short* __restrict__ W1h,
    unsigned short* __restrict__ ctxh, float* __restrict__ W2T)
{
    const int bid = blockIdx.x;
    if (bid < CVT_BLOCKS) {
        const int i4 = bid*256 + threadIdx.x;
        if (i4 < NX4) {
            ((ushort4*)Xh)[i4] = cvt4(((const float4*)X)[i4]);
        } else if (i4 < NX4 + NW14) {
            ((ushort4*)W1h)[i4 - NX4] = cvt4(((const float4*)W1)[i4 - NX4]);
        } else {
            const int j = i4 - NX4 - NW14;
            ((ushort4*)ctxh)[j] = cvt4(((const float4*)ctx)[j]);
        }
    } else {
        const int idx = (bid - CVT_BLOCKS)*256 + threadIdx.x;
        if (idx < 512*32) {
            const int j = idx >> 9, k = idx & 511;
            W2T[idx] = (j < 30) ? W2[k*30 + j] : 0.f;
        }
    }
}

// ---------------------------------------------------------------------------
// Kernel 1: GEMM1 via f16 MFMA 32x32x16, 64x64 tiles (proven config).
// ---------------------------------------------------------------------------
__global__ __launch_bounds__(256) void gemm1_kernel(
    const unsigned short* __restrict__ Xh, const unsigned short* __restrict__ W1h,
    const float* __restrict__ b1, unsigned short* __restrict__ Hh)
{
    __shared__ __align__(16) unsigned short As[64*72];
    __shared__ __align__(16) unsigned short Bs[64*72];
    const int row0 = (blockIdx.x >> 3) * 64;
    const int n0   = (blockIdx.x & 7)  * 64;
    const int tid  = threadIdx.x;
    const int lane = tid & 63, w = tid >> 6;
    const int wr = (w >> 1) * 32, wc = (w & 1) * 32;
    const int m  = lane & 31,  g  = lane >> 5;
    const int sa = tid >> 2,   ka = (tid & 3) * 16;
    const int kb = tid & 63,   wb = tid >> 6;

    f32x16 acc = {};

    for (int kt = 0; kt < DIN; kt += 64) {
        uint4 av0 = *(const uint4*)(Xh  + (size_t)(row0+sa)*DIN + kt + ka);
        uint4 av1 = *(const uint4*)(Xh  + (size_t)(row0+sa)*DIN + kt + ka + 8);
        uint4 bv0 = *(const uint4*)(W1h + (size_t)(kt+kb)*DF + n0 + wb*16);
        uint4 bv1 = *(const uint4*)(W1h + (size_t)(kt+kb)*DF + n0 + wb*16 + 8);
        __syncthreads();
        *(uint4*)(As + sa*72 + ka)     = av0;
        *(uint4*)(As + sa*72 + ka + 8) = av1;
        {
            union { uint4 u; unsigned short s[8]; } p0, p1;
            p0.u = bv0; p1.u = bv1;
            #pragma unroll
            for (int i = 0; i < 8; i++) Bs[(wb*16 + i)*72 + kb]     = p0.s[i];
            #pragma unroll
            for (int i = 0; i < 8; i++) Bs[(wb*16 + 8 + i)*72 + kb] = p1.s[i];
        }
        __syncthreads();
        #pragma unroll
        for (int ks = 0; ks < 64; ks += 16) {
            f16x8 af = *(const f16x8*)(As + (wr+m)*72 + ks + g*8);
            f16x8 bf = *(const f16x8*)(Bs + (wc+m)*72 + ks + g*8);
            acc = __builtin_amdgcn_mfma_f32_32x32x16_f16(af, bf, acc, 0, 0, 0);
        }
    }
    const int ncol = n0 + wc + m;
    const float bb = b1[ncol];
    #pragma unroll
    for (int r = 0; r < 16; r++) {
        const int rowloc = (r & 3) + 8*(r >> 2) + 4*g;
        const int row = row0 + wr + rowloc;
        float v = acc[r] + bb;
        v = v > 0.f ? v : 0.01f * v;
        Hh[(size_t)row*DF + ncol] = f2h(v);
    }
}

// ---------------------------------------------------------------------------
// Kernel 2: GEMM2 (8192x30, K=512); deltas -> d_ws, vars/wts -> outputs.
// ---------------------------------------------------------------------------
__global__ __launch_bounds__(256) void gemm2_kernel(
    const unsigned short* __restrict__ Hh, const float* __restrict__ W2T,
    const float* __restrict__ b2,
    float* __restrict__ deltas, float* __restrict__ dvars, float* __restrict__ dwts)
{
    __shared__ __align__(16) unsigned short Hs[32*520];
    const int tid = threadIdx.x;
    const int r0  = blockIdx.x * 32;
    {
        const uint4* src = (const uint4*)(Hh + (size_t)r0*DF);
        #pragma unroll
        for (int i = 0; i < 8; i++) {
            int u   = tid + i*256;
            int row = u >> 6;
            int col = (u & 63) * 8;
            *(uint4*)(Hs + row*520 + col) = src[u];
        }
    }
    __syncthreads();

    const int r  = tid & 31;
    const int j0 = tid >> 5;
    const unsigned short* hrow = Hs + r*520;
    float acc[4] = {0.f, 0.f, 0.f, 0.f};

    for (int k0 = 0; k0 < DF; k0 += 8) {
        union { uint4 u; _Float16 h[8]; } hv;
        hv.u = *(const uint4*)(hrow + k0);
        float wv[4][8];
        #pragma unroll
        for (int q = 0; q < 4; q++) {
            *(float4*)(wv[q])     = *(const float4*)(W2T + (size_t)(j0 + q*8)*DF + k0);
            *(float4*)(wv[q] + 4) = *(const float4*)(W2T + (size_t)(j0 + q*8)*DF + k0 + 4);
        }
        #pragma unroll
        for (int i = 0; i < 8; i++) {
            float hf = (float)hv.h[i];
            acc[0] = fmaf(hf, wv[0][i], acc[0]);
            acc[1] = fmaf(hf, wv[1][i], acc[1]);
            acc[2] = fmaf(hf, wv[2][i], acc[2]);
            acc[3] = fmaf(hf, wv[3][i], acc[3]);
        }
    }
    const int row = r0 + r;
    #pragma unroll
    for (int q = 0; q < 4; q++) {
        const int j = j0 + q*8;
        if (j >= 30) continue;
        float dot = acc[q] + b2[j];
        float sp  = fmaxf(dot, 0.f) + log1pf(__expf(-fabsf(dot)));
        if (j < 10)       deltas[row*NMIX + j]      = sp / 25.0f;
        else if (j < 20)  dvars [row*NMIX + (j-10)] = fminf(fmaxf(sp, 0.01f), 100.f);
        else              dwts  [row*NMIX + (j-20)] = sp;
    }
}

// ---------------------------------------------------------------------------
// Kernel 3: FUSED scan + attention.  Block = (b, 32-t chunk): 512 blocks,
// 512 threads.  Each block scans its b's deltas in registers (redundant per
// tc — cheap), tc==0 writes means output; means/vars/wts staged in LDS
// (stride 36, b128-aligned subgroups, broadcast reads), attn computed for
// all 512 s x 32 t, written f32 + f16.
// ---------------------------------------------------------------------------
__global__ __launch_bounds__(512) void attn_fused_kernel(
    const float* __restrict__ deltas, const float* __restrict__ initm,
    const float* __restrict__ vars_g, const float* __restrict__ wts_g,
    float* __restrict__ means_out, float* __restrict__ attn,
    unsigned short* __restrict__ attnh)
{
    __shared__ __align__(16) float mvw[256*36];   // 36.9 KB (one s-half)
    __shared__ float wsum[8][NMIX];
    const int bid  = blockIdx.x;
    const int b    = bid >> 5;
    const int tc   = bid & 31;
    const int tid  = threadIdx.x;          // s = tid
    const int lane = tid & 63, wid = tid >> 6;
    const int row  = tid*BATCH + b;

    float d[NMIX], vv[NMIX], ww[NMIX];
    #pragma unroll
    for (int k = 0; k < NMIX; k++) d[k]  = deltas[row*NMIX + k];
    #pragma unroll
    for (int k = 0; k < NMIX; k++) vv[k] = vars_g[row*NMIX + k];
    #pragma unroll
    for (int k = 0; k < NMIX; k++) ww[k] = wts_g[row*NMIX + k];

    // inclusive scan over s (wave shuffle + cross-wave LDS combine)
    #pragma unroll
    for (int k = 0; k < NMIX; k++) {
        #pragma unroll
        for (int dd = 1; dd < 64; dd <<= 1) {
            float t = __shfl_up(d[k], dd, 64);
            if (lane >= dd) d[k] += t;
        }
    }
    if (lane == 63) {
        #pragma unroll
        for (int k = 0; k < NMIX; k++) wsum[wid][k] = d[k];
    }
    __syncthreads();
    #pragma unroll
    for (int k = 0; k < NMIX; k++) {
        float base = initm[b*NMIX + k];
        for (int w2 = 0; w2 < wid; w2++) base += wsum[w2][k];
        d[k] += base;
    }
    if (tc == 0) {
        #pragma unroll
        for (int k = 0; k < NMIX; k++) means_out[row*NMIX + k] = d[k];
    }

    const int   t_idx = tc*32 + (tid & 31);
    const float tf    = (float)t_idx;
    const int   s_off = tid >> 5;          // 0..15

    for (int half = 0; half < 2; half++) {
        __syncthreads();                   // protect mvw reuse
        if ((tid >> 8) == half) {
            const int sl = tid & 255;
            #pragma unroll
            for (int k = 0; k < NMIX; k++) mvw[sl*36 + k]      = d[k];
            #pragma unroll
            for (int k = 0; k < NMIX; k++) mvw[sl*36 + 12 + k] = vv[k];
            #pragma unroll
            for (int k = 0; k < NMIX; k++) mvw[sl*36 + 24 + k] = ww[k];
        }
        __syncthreads();
        for (int si = 0; si < 256; si += 16) {
            const int sl = si + s_off;
            const int s  = half*256 + sl;
            const float* p = &mvw[sl*36];
            float m[NMIX], v[NMIX], w[NMIX];
            *(float4*)(m)     = *(const float4*)(p);
            *(float4*)(m + 4) = *(const float4*)(p + 4);
            *(float2*)(m + 8) = *(const float2*)(p + 8);
            *(float4*)(v)     = *(const float4*)(p + 12);
            *(float4*)(v + 4) = *(const float4*)(p + 16);
            *(float2*)(v + 8) = *(const float2*)(p + 20);
            *(float4*)(w)     = *(const float4*)(p + 24);
            *(float4*)(w + 4) = *(const float4*)(p + 28);
            *(float2*)(w + 8) = *(const float2*)(p + 32);
            float sum = 0.f;
            #pragma unroll
            for (int k = 0; k < NMIX; k++) {
                float dd = tf - m[k];
                sum += w[k] * __expf(-dd*dd*v[k]);
            }
            const size_t o = (size_t)(s*BATCH + b)*NCHAR + t_idx;
            attn[o]  = sum;
            attnh[o] = f2h(sum);
        }
    }
}

// ---------------------------------------------------------------------------
// Kernel 4: attended contexts via f16 MFMA, f16 inputs.
// ---------------------------------------------------------------------------
__global__ __launch_bounds__(256) void ctx_mfma_kernel(
    const unsigned short* __restrict__ attnh, const unsigned short* __restrict__ ctxh,
    float* __restrict__ out)
{
    __shared__ __align__(16) unsigned short As[64*72];
    __shared__ __align__(16) unsigned short Bs[64*72];
    const int bid  = blockIdx.x;
    const int b    = bid >> 5;
    const int rem  = bid & 31;
    const int s0   = (rem >> 2) * 64;
    const int d0   = (rem & 3)  * 64;
    const int tid  = threadIdx.x;
    const int lane = tid & 63, w = tid >> 6;
    const int wr = (w >> 1) * 32, wc = (w & 1) * 32;
    const int m  = lane & 31,  g  = lane >> 5;
    const int sl = tid >> 2,   tq = (tid & 3) * 16;
    const int tb = tid & 63,   db = (tid >> 6) * 16;

    f32x16 acc = {};
    const unsigned short* abase = attnh + (size_t)(s0+sl)*(BATCH*NCHAR) + b*NCHAR + tq;
    const unsigned short* bbase = ctxh  + (size_t)b*DCTX + d0 + db;

    for (int kt = 0; kt < NCHAR; kt += 64) {
        uint4 a0  = *(const uint4*)(abase + kt);
        uint4 a1  = *(const uint4*)(abase + kt + 8);
        uint4 bv0 = *(const uint4*)(bbase + (size_t)(kt+tb)*(BATCH*DCTX));
        uint4 bv1 = *(const uint4*)(bbase + (size_t)(kt+tb)*(BATCH*DCTX) + 8);
        __syncthreads();
        *(uint4*)(As + sl*72 + tq)     = a0;
        *(uint4*)(As + sl*72 + tq + 8) = a1;
        {
            union { uint4 u; unsigned short s[8]; } p0, p1;
            p0.u = bv0; p1.u = bv1;
            #pragma unroll
            for (int i = 0; i < 8; i++) Bs[(db + i)*72 + tb]     = p0.s[i];
            #pragma unroll
            for (int i = 0; i < 8; i++) Bs[(db + 8 + i)*72 + tb] = p1.s[i];
        }
        __syncthreads();
        #pragma unroll
        for (int ks = 0; ks < 64; ks += 16) {
            f16x8 af = *(const f16x8*)(As + (wr+m)*72 + ks + g*8);
            f16x8 bf = *(const f16x8*)(Bs + (wc+m)*72 + ks + g*8);
            acc = __builtin_amdgcn_mfma_f32_32x32x16_f16(af, bf, acc, 0, 0, 0);
        }
    }
    #pragma unroll
    for (int r = 0; r < 16; r++) {
        int rowloc = (r & 3) + 8*(r >> 2) + 4*g;
        int s = s0 + wr + rowloc;
        out[(size_t)s*(BATCH*DCTX) + b*DCTX + d0 + wc + m] = acc[r];
    }
}

// ---------------------------------------------------------------------------
extern "C" void kernel_launch(void* const* d_in, const int* in_sizes, int n_in,
                              void* d_out, int out_size, void* d_ws, size_t ws_size,
                              hipStream_t stream)
{
    const float* X     = (const float*)d_in[0];
    const float* ctx   = (const float*)d_in[1];
    const float* initm = (const float*)d_in[2];
    const float* W1    = (const float*)d_in[3];
    const float* b1    = (const float*)d_in[4];
    const float* W2    = (const float*)d_in[5];
    const float* b2    = (const float*)d_in[6];

    float* out      = (float*)d_out;
    float* out_ctx  = out + OFF_CTXOUT;
    float* out_attn = out + OFF_ATTN;
    float* out_mean = out + OFF_MEANS;
    float* out_var  = out + OFF_VARS;
    float* out_wts  = out + OFF_WTS;

    char* ws = (char*)d_ws;
    unsigned short* Xh    = (unsigned short*)(ws + WS_XH);
    unsigned short* W1h   = (unsigned short*)(ws + WS_W1H);
    float*          W2T   = (float*)         (ws + WS_W2T);
    unsigned short* Hh    = (unsigned short*)(ws + WS_HH);
    unsigned short* ctxh  = (unsigned short*)(ws + WS_CTXH);
    unsigned short* attnh = (unsigned short*)(ws + WS_ATTNH);
    float*          delt  = (float*)         (ws + WS_DELTA);

    convert_kernel<<<CVT_BLOCKS + W2T_BLOCKS, 256, 0, stream>>>(
        X, W1, ctx, W2, Xh, W1h, ctxh, W2T);
    gemm1_kernel<<<(M_ROWS/64)*(DF/64), 256, 0, stream>>>(Xh, W1h, b1, Hh);
    gemm2_kernel<<<M_ROWS/32, 256, 0, stream>>>(Hh, W2T, b2, delt, out_var, out_wts);
    attn_fused_kernel<<<BATCH*32, 512, 0, stream>>>(
        delt, initm, out_var, out_wts, out_mean, out_attn, attnh);
    ctx_mfma_kernel<<<16*8*4, 256, 0, stream>>>(attnh, ctxh, out_ctx);
}

// Round 8
// 152.168 us; speedup vs baseline: 1.1768x; 1.1768x over previous
//
#include <hip/hip_runtime.h>
#include <math.h>

#define S_LEN 512
#define BATCH 16
#define DIN   512
#define DF    512
#define NMIX  10
#define NCHAR 1024
#define DCTX  256
#define M_ROWS (S_LEN*BATCH)   // 8192

// d_out layout (tuple flattened in return order)
#define OFF_CTXOUT 0
#define OFF_ATTN   (S_LEN*BATCH*DCTX)
#define OFF_MEANS  (OFF_ATTN + S_LEN*BATCH*NCHAR)
#define OFF_VARS   (OFF_MEANS + S_LEN*BATCH*NMIX)
#define OFF_WTS    (OFF_VARS  + S_LEN*BATCH*NMIX)

// scratch layout in d_ws (byte offsets)
#define WS_XH    0            // f16  8 MB   (8192x512)
#define WS_W1H   (8u<<20)     // f16  512 KB
#define WS_W2T   (9u<<20)     // f32  64 KB  (32x512 padded)
#define WS_HH    (10u<<20)    // f16  8 MB
#define WS_CTXH  (18u<<20)    // f16  8 MB
#define WS_ATTNH (26u<<20)    // f16  16.8 MB
#define WS_BOUND (44u<<20)    // u32  16     per-batch reach bound (float bits)

#define NX4     1048576
#define NW14    65536
#define NCTX4   1048576
#define CVT4    (NX4 + NW14 + NCTX4)
#define CVT_BLOCKS (CVT4/256)
#define W2T_BLOCKS 64

typedef float    f32x16 __attribute__((ext_vector_type(16)));
typedef _Float16 f16x8  __attribute__((ext_vector_type(8)));

__device__ __forceinline__ unsigned short f2h(float x) {
    union { _Float16 h; unsigned short u; } cv;
    cv.h = (_Float16)x;
    return cv.u;
}
__device__ __forceinline__ ushort4 cvt4(float4 v) {
    ushort4 o; o.x = f2h(v.x); o.y = f2h(v.y); o.z = f2h(v.z); o.w = f2h(v.w);
    return o;
}

// ---------------------------------------------------------------------------
// Kernel 0: convert X,W1,ctx -> f16; W2^T (fp32, 32 rows); zero bound[16].
// ---------------------------------------------------------------------------
__global__ __launch_bounds__(256) void convert_kernel(
    const float* __restrict__ X, const float* __restrict__ W1,
    const float* __restrict__ ctx, const float* __restrict__ W2,
    unsigned short* __restrict__ Xh, unsigned short* __restrict__ W1h,
    unsigned short* __restrict__ ctxh, float* __restrict__ W2T,
    unsigned int* __restrict__ bound)
{
    const int bid = blockIdx.x;
    if (bid < CVT_BLOCKS) {
        const int i4 = bid*256 + threadIdx.x;
        if (i4 < NX4) {
            ((ushort4*)Xh)[i4] = cvt4(((const float4*)X)[i4]);
        } else if (i4 < NX4 + NW14) {
            ((ushort4*)W1h)[i4 - NX4] = cvt4(((const float4*)W1)[i4 - NX4]);
        } else {
            const int j = i4 - NX4 - NW14;
            ((ushort4*)ctxh)[j] = cvt4(((const float4*)ctx)[j]);
        }
    } else if (bid < CVT_BLOCKS + W2T_BLOCKS) {
        const int idx = (bid - CVT_BLOCKS)*256 + threadIdx.x;
        if (idx < 512*32) {
            const int j = idx >> 9, k = idx & 511;
            W2T[idx] = (j < 30) ? W2[k*30 + j] : 0.f;
        }
    } else {
        if (threadIdx.x < BATCH) bound[threadIdx.x] = 0u;
    }
}

// ---------------------------------------------------------------------------
// Kernel 1: GEMM1 via f16 MFMA 32x32x16, 64x64 tiles (proven config).
// ---------------------------------------------------------------------------
__global__ __launch_bounds__(256) void gemm1_kernel(
    const unsigned short* __restrict__ Xh, const unsigned short* __restrict__ W1h,
    const float* __restrict__ b1, unsigned short* __restrict__ Hh)
{
    __shared__ __align__(16) unsigned short As[64*72];
    __shared__ __align__(16) unsigned short Bs[64*72];
    const int row0 = (blockIdx.x >> 3) * 64;
    const int n0   = (blockIdx.x & 7)  * 64;
    const int tid  = threadIdx.x;
    const int lane = tid & 63, w = tid >> 6;
    const int wr = (w >> 1) * 32, wc = (w & 1) * 32;
    const int m  = lane & 31,  g  = lane >> 5;
    const int sa = tid >> 2,   ka = (tid & 3) * 16;
    const int kb = tid & 63,   wb = tid >> 6;

    f32x16 acc = {};

    for (int kt = 0; kt < DIN; kt += 64) {
        uint4 av0 = *(const uint4*)(Xh  + (size_t)(row0+sa)*DIN + kt + ka);
        uint4 av1 = *(const uint4*)(Xh  + (size_t)(row0+sa)*DIN + kt + ka + 8);
        uint4 bv0 = *(const uint4*)(W1h + (size_t)(kt+kb)*DF + n0 + wb*16);
        uint4 bv1 = *(const uint4*)(W1h + (size_t)(kt+kb)*DF + n0 + wb*16 + 8);
        __syncthreads();
        *(uint4*)(As + sa*72 + ka)     = av0;
        *(uint4*)(As + sa*72 + ka + 8) = av1;
        {
            union { uint4 u; unsigned short s[8]; } p0, p1;
            p0.u = bv0; p1.u = bv1;
            #pragma unroll
            for (int i = 0; i < 8; i++) Bs[(wb*16 + i)*72 + kb]     = p0.s[i];
            #pragma unroll
            for (int i = 0; i < 8; i++) Bs[(wb*16 + 8 + i)*72 + kb] = p1.s[i];
        }
        __syncthreads();
        #pragma unroll
        for (int ks = 0; ks < 64; ks += 16) {
            f16x8 af = *(const f16x8*)(As + (wr+m)*72 + ks + g*8);
            f16x8 bf = *(const f16x8*)(Bs + (wc+m)*72 + ks + g*8);
            acc = __builtin_amdgcn_mfma_f32_32x32x16_f16(af, bf, acc, 0, 0, 0);
        }
    }
    const int ncol = n0 + wc + m;
    const float bb = b1[ncol];
    #pragma unroll
    for (int r = 0; r < 16; r++) {
        const int rowloc = (r & 3) + 8*(r >> 2) + 4*g;
        const int row = row0 + wr + rowloc;
        float v = acc[r] + bb;
        v = v > 0.f ? v : 0.01f * v;
        Hh[(size_t)row*DF + ncol] = f2h(v);
    }
}

// ---------------------------------------------------------------------------
// Kernel 2: GEMM2 (8192x30, K=512); deltas -> means region (scanned next).
// ---------------------------------------------------------------------------
__global__ __launch_bounds__(256) void gemm2_kernel(
    const unsigned short* __restrict__ Hh, const float* __restrict__ W2T,
    const float* __restrict__ b2,
    float* __restrict__ dmeans, float* __restrict__ dvars, float* __restrict__ dwts)
{
    __shared__ __align__(16) unsigned short Hs[32*520];
    const int tid = threadIdx.x;
    const int r0  = blockIdx.x * 32;
    {
        const uint4* src = (const uint4*)(Hh + (size_t)r0*DF);
        #pragma unroll
        for (int i = 0; i < 8; i++) {
            int u   = tid + i*256;
            int row = u >> 6;
            int col = (u & 63) * 8;
            *(uint4*)(Hs + row*520 + col) = src[u];
        }
    }
    __syncthreads();

    const int r  = tid & 31;
    const int j0 = tid >> 5;
    const unsigned short* hrow = Hs + r*520;
    float acc[4] = {0.f, 0.f, 0.f, 0.f};

    for (int k0 = 0; k0 < DF; k0 += 8) {
        union { uint4 u; _Float16 h[8]; } hv;
        hv.u = *(const uint4*)(hrow + k0);
        float wv[4][8];
        #pragma unroll
        for (int q = 0; q < 4; q++) {
            *(float4*)(wv[q])     = *(const float4*)(W2T + (size_t)(j0 + q*8)*DF + k0);
            *(float4*)(wv[q] + 4) = *(const float4*)(W2T + (size_t)(j0 + q*8)*DF + k0 + 4);
        }
        #pragma unroll
        for (int i = 0; i < 8; i++) {
            float hf = (float)hv.h[i];
            acc[0] = fmaf(hf, wv[0][i], acc[0]);
            acc[1] = fmaf(hf, wv[1][i], acc[1]);
            acc[2] = fmaf(hf, wv[2][i], acc[2]);
            acc[3] = fmaf(hf, wv[3][i], acc[3]);
        }
    }
    const int row = r0 + r;
    #pragma unroll
    for (int q = 0; q < 4; q++) {
        const int j = j0 + q*8;
        if (j >= 30) continue;
        float dot = acc[q] + b2[j];
        float sp  = fmaxf(dot, 0.f) + log1pf(__expf(-fabsf(dot)));
        if (j < 10)       dmeans[row*NMIX + j]      = sp / 25.0f;
        else if (j < 20)  dvars [row*NMIX + (j-10)] = fminf(fmaxf(sp, 0.01f), 100.f);
        else              dwts  [row*NMIX + (j-20)] = sp;
    }
}

// ---------------------------------------------------------------------------
// Kernel 3: scan (in-place on means region) + per-batch reach bound.
// reach = mean + 4.8/sqrt(var)  (exp(-23)=1e-10 beyond); atomicMax as int
// bits (all values positive).
// ---------------------------------------------------------------------------
__global__ __launch_bounds__(512) void scan_kernel(
    const float* __restrict__ init_means, float* __restrict__ means,
    const float* __restrict__ vars_g, unsigned int* __restrict__ bound)
{
    const int p    = blockIdx.x;          // b*NMIX + k
    const int s    = threadIdx.x;
    const int lane = s & 63;
    const int wid  = s >> 6;

    float x = means[s*(BATCH*NMIX) + p];
    #pragma unroll
    for (int d = 1; d < 64; d <<= 1) {
        float tv = __shfl_up(x, d, 64);
        if (lane >= d) x += tv;
    }
    __shared__ float wsum[8];
    __shared__ float wmax[8];
    if (lane == 63) wsum[wid] = x;
    __syncthreads();
    float off = init_means[p];
    for (int i = 0; i < wid; i++) off += wsum[i];
    x += off;
    means[s*(BATCH*NMIX) + p] = x;

    // reach bound
    float v = vars_g[s*(BATCH*NMIX) + p];
    float reach = x + 4.8f * rsqrtf(v);
    #pragma unroll
    for (int d = 32; d >= 1; d >>= 1)
        reach = fmaxf(reach, __shfl_xor(reach, d, 64));
    if (lane == 0) wmax[wid] = reach;
    __syncthreads();
    if (s == 0) {
        float mx = wmax[0];
        #pragma unroll
        for (int i = 1; i < 8; i++) mx = fmaxf(mx, wmax[i]);
        atomicMax((int*)&bound[p / NMIX], __float_as_int(mx));
    }
}

// ---------------------------------------------------------------------------
// Kernel 4: attention weights.  Zero fast-path beyond per-batch bound;
// attnh only written for t < kmax (all ctx ever reads).
// ---------------------------------------------------------------------------
__global__ __launch_bounds__(256) void attn_kernel(
    const float* __restrict__ means, const float* __restrict__ vars,
    const float* __restrict__ wts,   const unsigned int* __restrict__ bound,
    float* __restrict__ attn, unsigned short* __restrict__ attnh)
{
    const int row = blockIdx.x;
    const int b   = row & (BATCH-1);
    const int tid = threadIdx.x;
    const int bd  = (int)__int_as_float((int)bound[b]);
    const int kmax = min(NCHAR, (bd + 64) & ~63);
    const int t0  = tid * 4;

    float o[4] = {0.f, 0.f, 0.f, 0.f};
    if (t0 <= bd) {
        float m[NMIX], v[NMIX], w[NMIX];
        #pragma unroll
        for (int k = 0; k < NMIX; k++) {
            m[k] = means[row*NMIX + k];
            v[k] = vars [row*NMIX + k];
            w[k] = wts  [row*NMIX + k];
        }
        #pragma unroll
        for (int i = 0; i < 4; i++) {
            const float t = (float)(t0 + i);
            float sum = 0.f;
            #pragma unroll
            for (int k = 0; k < NMIX; k++) {
                float d = t - m[k];
                sum += w[k] * __expf(-d*d*v[k]);
            }
            o[i] = sum;
        }
    }
    *(float4*)(attn + (size_t)row*NCHAR + t0) = make_float4(o[0],o[1],o[2],o[3]);
    if (t0 < kmax) {
        ushort4 h; h.x = f2h(o[0]); h.y = f2h(o[1]); h.z = f2h(o[2]); h.w = f2h(o[3]);
        *(ushort4*)(attnh + (size_t)row*NCHAR + t0) = h;
    }
}

// ---------------------------------------------------------------------------
// Kernel 5: attended contexts via f16 MFMA; K-loop clipped to kmax[b].
// ---------------------------------------------------------------------------
__global__ __launch_bounds__(256) void ctx_mfma_kernel(
    const unsigned short* __restrict__ attnh, const unsigned short* __restrict__ ctxh,
    const unsigned int* __restrict__ bound, float* __restrict__ out)
{
    __shared__ __align__(16) unsigned short As[64*72];
    __shared__ __align__(16) unsigned short Bs[64*72];
    const int bid  = blockIdx.x;
    const int b    = bid >> 5;
    const int rem  = bid & 31;
    const int s0   = (rem >> 2) * 64;
    const int d0   = (rem & 3)  * 64;
    const int tid  = threadIdx.x;
    const int lane = tid & 63, w = tid >> 6;
    const int wr = (w >> 1) * 32, wc = (w & 1) * 32;
    const int m  = lane & 31,  g  = lane >> 5;
    const int sl = tid >> 2,   tq = (tid & 3) * 16;
    const int tb = tid & 63,   db = (tid >> 6) * 16;

    const int bd   = (int)__int_as_float((int)bound[b]);
    const int kmax = min(NCHAR, (bd + 64) & ~63);

    f32x16 acc = {};
    const unsigned short* abase = attnh + (size_t)(s0+sl)*(BATCH*NCHAR) + b*NCHAR + tq;
    const unsigned short* bbase = ctxh  + (size_t)b*DCTX + d0 + db;

    for (int kt = 0; kt < kmax; kt += 64) {
        uint4 a0  = *(const uint4*)(abase + kt);
        uint4 a1  = *(const uint4*)(abase + kt + 8);
        uint4 bv0 = *(const uint4*)(bbase + (size_t)(kt+tb)*(BATCH*DCTX));
        uint4 bv1 = *(const uint4*)(bbase + (size_t)(kt+tb)*(BATCH*DCTX) + 8);
        __syncthreads();
        *(uint4*)(As + sl*72 + tq)     = a0;
        *(uint4*)(As + sl*72 + tq + 8) = a1;
        {
            union { uint4 u; unsigned short s[8]; } p0, p1;
            p0.u = bv0; p1.u = bv1;
            #pragma unroll
            for (int i = 0; i < 8; i++) Bs[(db + i)*72 + tb]     = p0.s[i];
            #pragma unroll
            for (int i = 0; i < 8; i++) Bs[(db + 8 + i)*72 + tb] = p1.s[i];
        }
        __syncthreads();
        #pragma unroll
        for (int ks = 0; ks < 64; ks += 16) {
            f16x8 af = *(const f16x8*)(As + (wr+m)*72 + ks + g*8);
            f16x8 bf = *(const f16x8*)(Bs + (wc+m)*72 + ks + g*8);
            acc = __builtin_amdgcn_mfma_f32_32x32x16_f16(af, bf, acc, 0, 0, 0);
        }
    }
    #pragma unroll
    for (int r = 0; r < 16; r++) {
        int rowloc = (r & 3) + 8*(r >> 2) + 4*g;
        int s = s0 + wr + rowloc;
        out[(size_t)s*(BATCH*DCTX) + b*DCTX + d0 + wc + m] = acc[r];
    }
}

// ---------------------------------------------------------------------------
extern "C" void kernel_launch(void* const* d_in, const int* in_sizes, int n_in,
                              void* d_out, int out_size, void* d_ws, size_t ws_size,
                              hipStream_t stream)
{
    const float* X     = (const float*)d_in[0];
    const float* ctx   = (const float*)d_in[1];
    const float* initm = (const float*)d_in[2];
    const float* W1    = (const float*)d_in[3];
    const float* b1    = (const float*)d_in[4];
    const float* W2    = (const float*)d_in[5];
    const float* b2    = (const float*)d_in[6];

    float* out      = (float*)d_out;
    float* out_ctx  = out + OFF_CTXOUT;
    float* out_attn = out + OFF_ATTN;
    float* out_mean = out + OFF_MEANS;
    float* out_var  = out + OFF_VARS;
    float* out_wts  = out + OFF_WTS;

    char* ws = (char*)d_ws;
    unsigned short* Xh    = (unsigned short*)(ws + WS_XH);
    unsigned short* W1h   = (unsigned short*)(ws + WS_W1H);
    float*          W2T   = (float*)         (ws + WS_W2T);
    unsigned short* Hh    = (unsigned short*)(ws + WS_HH);
    unsigned short* ctxh  = (unsigned short*)(ws + WS_CTXH);
    unsigned short* attnh = (unsigned short*)(ws + WS_ATTNH);
    unsigned int*   bnd   = (unsigned int*)  (ws + WS_BOUND);

    convert_kernel<<<CVT_BLOCKS + W2T_BLOCKS + 1, 256, 0, stream>>>(
        X, W1, ctx, W2, Xh, W1h, ctxh, W2T, bnd);
    gemm1_kernel<<<(M_ROWS/64)*(DF/64), 256, 0, stream>>>(Xh, W1h, b1, Hh);
    gemm2_kernel<<<M_ROWS/32, 256, 0, stream>>>(Hh, W2T, b2, out_mean, out_var, out_wts);
    scan_kernel<<<BATCH*NMIX, 512, 0, stream>>>(initm, out_mean, out_var, bnd);
    attn_kernel<<<M_ROWS, 256, 0, stream>>>(out_mean, out_var, out_wts, bnd,
                                            out_attn, attnh);
    ctx_mfma_kernel<<<16*8*4, 256, 0, stream>>>(attnh, ctxh, bnd, out_ctx);
}